// Round 3
// baseline (367.199 us; speedup 1.0000x reference)
//
#include <hip/hip_runtime.h>

#define F_IN  128
#define H_MID 16
#define C_OUT 8
#define XS_PAD (F_IN + 4)

// ================= common small kernels =================
__global__ void k_init(float* __restrict__ deg, int* __restrict__ count,
                       int* __restrict__ cursor, int N) {
    int i = blockIdx.x * blockDim.x + threadIdx.x;
    if (i < N) { deg[i] = 1.0f; count[i] = 0; cursor[i] = 0; }
}

__global__ void k_hist(const int* __restrict__ dst, const float* __restrict__ ew,
                       float* __restrict__ deg, int* __restrict__ count, int E) {
    int e = blockIdx.x * blockDim.x + threadIdx.x;
    if (e < E) {
        int d = dst[e];
        atomicAdd(&deg[d], ew[e]);
        atomicAdd(&count[d], 1);
    }
}

__global__ void k_rsqrt(float* __restrict__ deg, int N) {
    int i = blockIdx.x * blockDim.x + threadIdx.x;
    if (i < N) {
        float v = deg[i];
        deg[i] = (v > 0.0f) ? rsqrtf(v) : 0.0f;
    }
}

// ================= hierarchical exclusive scan (count -> rowptr) =================
__global__ void __launch_bounds__(1024) k_scan1(const int* __restrict__ count,
                                                int* __restrict__ rowptr,
                                                int* __restrict__ bsum, int N) {
    __shared__ int s[1024];
    const int t = threadIdx.x;
    const int g = blockIdx.x * 1024 + t;
    int v = (g < N) ? count[g] : 0;
    s[t] = v; __syncthreads();
#pragma unroll
    for (int off = 1; off < 1024; off <<= 1) {
        int u = (t >= off) ? s[t - off] : 0; __syncthreads();
        s[t] += u; __syncthreads();
    }
    if (g < N) rowptr[g] = s[t] - v;            // exclusive within block
    if (t == 1023) bsum[blockIdx.x] = s[1023];  // block total
}

__global__ void __launch_bounds__(1024) k_scan2(int* __restrict__ bsum, int nb) {
    __shared__ int s[1024];
    const int t = threadIdx.x;
    int v = (t < nb) ? bsum[t] : 0;
    s[t] = v; __syncthreads();
#pragma unroll
    for (int off = 1; off < 1024; off <<= 1) {
        int u = (t >= off) ? s[t - off] : 0; __syncthreads();
        s[t] += u; __syncthreads();
    }
    if (t < nb) bsum[t] = s[t] - v;             // exclusive
}

__global__ void k_scan3(int* __restrict__ rowptr, const int* __restrict__ bsum,
                        int N, int E) {
    int g = blockIdx.x * blockDim.x + threadIdx.x;
    if (g < N) rowptr[g] += bsum[g >> 10];
    else if (g == N) rowptr[N] = E;
}

// ================= scatter edges into CSR order, packing {src, norm} =================
__global__ void k_scatter_sort(const int* __restrict__ src, const int* __restrict__ dst,
                               const float* __restrict__ ew, const float* __restrict__ dis,
                               const int* __restrict__ rowptr, int* __restrict__ cursor,
                               int2* __restrict__ ed, int E) {
    int e = blockIdx.x * blockDim.x + threadIdx.x;
    if (e < E) {
        const int s = src[e];
        const int d = dst[e];
        const float norm = dis[s] * ew[e] * dis[d];
        const int pos = rowptr[d] + atomicAdd(&cursor[d], 1);
        ed[pos] = make_int2(s, __float_as_int(norm));
    }
}

// ================= layer-1 GEMM (LDS-staged) =================
__global__ void __launch_bounds__(256) k_gemm1(
        const float* __restrict__ x, const float* __restrict__ W1,
        const float* __restrict__ b1, const float* __restrict__ dis,
        float* __restrict__ h1, float* __restrict__ a1, int N) {
    __shared__ float xs[64 * XS_PAD];
    __shared__ float W1s[F_IN * H_MID];
    const int t = threadIdx.x;
    for (int i = t; i < F_IN * H_MID; i += 256) W1s[i] = W1[i];

    const int c  = t & 15;
    const int r0 = t >> 4;

    for (long long tile = (long long)blockIdx.x * 64; tile < N;
         tile += (long long)gridDim.x * 64) {
        const int rows = (int)((N - tile < 64) ? (N - tile) : 64);
        __syncthreads();
        const int nf4 = rows * (F_IN / 4);
        const float4* xg = reinterpret_cast<const float4*>(x + tile * F_IN);
        for (int i = t; i < nf4; i += 256) {
            const int r  = i >> 5;
            const int k4 = i & 31;
            *reinterpret_cast<float4*>(&xs[r * XS_PAD + k4 * 4]) = xg[i];
        }
        __syncthreads();
        for (int rr = r0; rr < rows; rr += 16) {
            const float* xr = &xs[rr * XS_PAD];
            float acc = 0.0f;
#pragma unroll
            for (int k4 = 0; k4 < F_IN / 4; ++k4) {
                float4 v = *reinterpret_cast<const float4*>(&xr[k4 * 4]);
                acc = fmaf(v.x, W1s[(k4 * 4 + 0) * H_MID + c], acc);
                acc = fmaf(v.y, W1s[(k4 * 4 + 1) * H_MID + c], acc);
                acc = fmaf(v.z, W1s[(k4 * 4 + 2) * H_MID + c], acc);
                acc = fmaf(v.w, W1s[(k4 * 4 + 3) * H_MID + c], acc);
            }
            const long long row = tile + rr;
            h1[row * H_MID + c] = acc;
            float di = dis[row];
            a1[row * H_MID + c] = fmaf(acc, di * di, b1[c]);
        }
    }
}

// ================= CSR aggregation (atomic-free) =================
// CH threads per node; out[node*CH+c] += sum over node's edge segment.
template <int LOG>
__global__ void k_agg_csr(const int* __restrict__ rowptr, const int2* __restrict__ ed,
                          const float* __restrict__ h, float* __restrict__ out, int N) {
    const int CH = 1 << LOG;
    const long long t = (long long)blockIdx.x * blockDim.x + threadIdx.x;
    const int node = (int)(t >> LOG);
    const int c = (int)(t & (CH - 1));
    if (node >= N) return;
    const int beg = rowptr[node];
    const int end = rowptr[node + 1];
    float acc0 = 0.0f, acc1 = 0.0f;
    int e = beg;
    for (; e + 1 < end; e += 2) {
        int2 p0 = ed[e];
        int2 p1 = ed[e + 1];
        acc0 = fmaf(h[(long long)p0.x * CH + c], __int_as_float(p0.y), acc0);
        acc1 = fmaf(h[(long long)p1.x * CH + c], __int_as_float(p1.y), acc1);
    }
    if (e < end) {
        int2 p = ed[e];
        acc0 = fmaf(h[(long long)p.x * CH + c], __int_as_float(p.y), acc0);
    }
    out[(long long)node * CH + c] += acc0 + acc1;
}

// ================= layer-2 GEMM =================
__global__ void k_gemm2(const float* __restrict__ a1, const float* __restrict__ W2,
                        const float* __restrict__ b2, const float* __restrict__ dis,
                        float* __restrict__ h2, float* __restrict__ out, int N) {
    __shared__ float W2s[H_MID * C_OUT];
    if (threadIdx.x < H_MID * C_OUT) W2s[threadIdx.x] = W2[threadIdx.x];
    __syncthreads();
    const int c   = threadIdx.x & 7;
    const int lr  = threadIdx.x >> 3;
    const int rpb = blockDim.x >> 3;
    for (long long row = (long long)blockIdx.x * rpb + lr; row < N;
         row += (long long)gridDim.x * rpb) {
        const float4* ar = reinterpret_cast<const float4*>(a1 + row * H_MID);
        float acc = 0.0f;
#pragma unroll
        for (int k4 = 0; k4 < H_MID / 4; ++k4) {
            float4 v = ar[k4];
            acc = fmaf(fmaxf(v.x, 0.0f), W2s[(k4 * 4 + 0) * C_OUT + c], acc);
            acc = fmaf(fmaxf(v.y, 0.0f), W2s[(k4 * 4 + 1) * C_OUT + c], acc);
            acc = fmaf(fmaxf(v.z, 0.0f), W2s[(k4 * 4 + 2) * C_OUT + c], acc);
            acc = fmaf(fmaxf(v.w, 0.0f), W2s[(k4 * 4 + 3) * C_OUT + c], acc);
        }
        h2[row * C_OUT + c] = acc;
        float di = dis[row];
        out[row * C_OUT + c] = fmaf(acc, di * di, b2[c]);
    }
}

// ================= fallback (round-2 atomic path) =================
template <int CH>
__global__ void k_agg(const int* __restrict__ src, const int* __restrict__ dst,
                      const float* __restrict__ ew, const float* __restrict__ dis,
                      const float* __restrict__ h, float* __restrict__ out, long long E) {
    const int LOG = (CH == 16) ? 4 : 3;
    const long long total  = E << LOG;
    const long long stride = (long long)gridDim.x * blockDim.x;
    for (long long idx = (long long)blockIdx.x * blockDim.x + threadIdx.x; idx < total;
         idx += stride) {
        const long long e = idx >> LOG;
        const int c = (int)(idx & (CH - 1));
        const int s = src[e];
        const int d = dst[e];
        const float norm = dis[s] * ew[e] * dis[d];
        atomicAdd(out + (long long)d * CH + c, h[(long long)s * CH + c] * norm);
    }
}

__global__ void k_scatter_deg(const int* __restrict__ dst, const float* __restrict__ ew,
                              float* __restrict__ deg, int E) {
    int e = blockIdx.x * blockDim.x + threadIdx.x;
    if (e < E) atomicAdd(&deg[dst[e]], ew[e]);
}

__global__ void k_init_deg(float* __restrict__ deg, int N) {
    int i = blockIdx.x * blockDim.x + threadIdx.x;
    if (i < N) deg[i] = 1.0f;
}

extern "C" void kernel_launch(void* const* d_in, const int* in_sizes, int n_in,
                              void* d_out, int out_size, void* d_ws, size_t ws_size,
                              hipStream_t stream) {
    const float* x  = (const float*)d_in[0];
    const int*   ei = (const int*)d_in[1];
    const float* ew = (const float*)d_in[2];
    const float* W1 = (const float*)d_in[3];
    const float* b1 = (const float*)d_in[4];
    const float* W2 = (const float*)d_in[5];
    const float* b2 = (const float*)d_in[6];
    float* out = (float*)d_out;

    const int H   = in_sizes[4];            // 16
    const int Fin = in_sizes[3] / H;        // 128
    const int N   = in_sizes[0] / Fin;      // 100000
    const long long E = in_sizes[2];        // 1600000
    const int* src = ei;
    const int* dst = ei + E;

    char* ws = (char*)d_ws;
    size_t off = 0;
    auto alloc = [&](size_t bytes) {
        void* p = ws + off;
        off = (off + bytes + 255) & ~(size_t)255;
        return p;
    };
    float* dis   = (float*)alloc((size_t)N * sizeof(float));
    float* h1    = (float*)alloc((size_t)N * H_MID * sizeof(float));
    float* a1    = (float*)alloc((size_t)N * H_MID * sizeof(float));
    float* h2    = (float*)alloc((size_t)N * C_OUT * sizeof(float));
    // CSR extras
    int*   count  = (int*)alloc((size_t)N * sizeof(int));
    int*   cursor = (int*)alloc((size_t)N * sizeof(int));
    int*   rowptr = (int*)alloc(((size_t)N + 1) * sizeof(int));
    int*   bsum   = (int*)alloc(1024 * sizeof(int));
    int2*  ed     = (int2*)alloc((size_t)E * sizeof(int2));
    const size_t needed = off;
    (void)n_in; (void)out_size;

    const int B = 256;
    const int nb1024 = (N + 1023) >> 10;    // scan blocks
    const bool csr_ok = (needed <= ws_size) && (nb1024 <= 1024);

    if (csr_ok) {
        // 1. init + histogram (count, weighted degree)
        k_init<<<(N + B - 1) / B, B, 0, stream>>>(dis, count, cursor, N);
        k_hist<<<(int)((E + B - 1) / B), B, 0, stream>>>(dst, ew, dis, count, (int)E);
        k_rsqrt<<<(N + B - 1) / B, B, 0, stream>>>(dis, N);
        // 2. exclusive scan count -> rowptr
        k_scan1<<<nb1024, 1024, 0, stream>>>(count, rowptr, bsum, N);
        k_scan2<<<1, 1024, 0, stream>>>(bsum, nb1024);
        k_scan3<<<(N + 1 + B - 1) / B, B, 0, stream>>>(rowptr, bsum, N, (int)E);
        // 3. scatter edges into CSR slots with precomputed norm
        k_scatter_sort<<<(int)((E + B - 1) / B), B, 0, stream>>>(
            src, dst, ew, dis, rowptr, cursor, ed, (int)E);
        // 4. layer 1
        k_gemm1<<<(N + 63) / 64, B, 0, stream>>>(x, W1, b1, dis, h1, a1, N);
        k_agg_csr<4><<<(int)(((long long)N * H_MID + B - 1) / B), B, 0, stream>>>(
            rowptr, ed, h1, a1, N);
        // 5. layer 2
        k_gemm2<<<(N + 31) / 32, B, 0, stream>>>(a1, W2, b2, dis, h2, out, N);
        k_agg_csr<3><<<(int)(((long long)N * C_OUT + B - 1) / B), B, 0, stream>>>(
            rowptr, ed, h2, out, N);
    } else {
        // fallback: round-2 atomic path (fits in 17 MB)
        k_init_deg<<<(N + B - 1) / B, B, 0, stream>>>(dis, N);
        k_scatter_deg<<<(int)((E + B - 1) / B), B, 0, stream>>>(dst, ew, dis, (int)E);
        k_rsqrt<<<(N + B - 1) / B, B, 0, stream>>>(dis, N);
        k_gemm1<<<(N + 63) / 64, B, 0, stream>>>(x, W1, b1, dis, h1, a1, N);
        k_agg<H_MID><<<8192, B, 0, stream>>>(src, dst, ew, dis, h1, a1, E);
        k_gemm2<<<(N + 31) / 32, B, 0, stream>>>(a1, W2, b2, dis, h2, out, N);
        k_agg<C_OUT><<<8192, B, 0, stream>>>(src, dst, ew, dis, h2, out, E);
    }
}

// Round 4
// 193.001 us; speedup vs baseline: 1.9026x; 1.9026x over previous
//
#include <hip/hip_runtime.h>

#define F_IN  128
#define H_MID 16
#define C_OUT 8
#define XS_PAD (F_IN + 4)
#define CHUNK 4096          // edges per k_bscatter block
#define NBMAX 512           // bucket array size (NB = ceil(N/256) <= 512)

// ======================================================================
// Bucketed counting-sort CSR build (atomic-light).
// Bucket of dst d = d>>8 (256 dst per bucket). Edge record packed as
// int2 { src | (d&255)<<18 , float_bits(ew) }  -- requires N <= 262143.
// ======================================================================

// ---- pass A: bucket histogram -> bcount (global, LDS-staged atomics) ----
__global__ void __launch_bounds__(256) k_bhist(const int* __restrict__ dst,
                                               int* __restrict__ bcount,
                                               int E, int NB) {
    __shared__ int hist[NBMAX];
    const int t = threadIdx.x;
    for (int l = t; l < NBMAX; l += 256) hist[l] = 0;
    __syncthreads();
    for (int i = blockIdx.x * 256 + t; i < E; i += gridDim.x * 256)
        atomicAdd(&hist[((unsigned)dst[i]) >> 8], 1);
    __syncthreads();
    for (int l = t; l < NB; l += 256)
        if (hist[l]) atomicAdd(&bcount[l], hist[l]);
}

// ---- pass B0: exclusive scan bcount -> bptr, init bcursor (1 block) ----
__global__ void __launch_bounds__(512) k_bscan(const int* __restrict__ bcount,
                                               int* __restrict__ bptr,
                                               int* __restrict__ bcursor,
                                               int NB, int E) {
    __shared__ int s[512];
    const int t = threadIdx.x;
    const int v = (t < NB) ? bcount[t] : 0;
    s[t] = v;
    __syncthreads();
#pragma unroll
    for (int off = 1; off < 512; off <<= 1) {
        int u = (t >= off) ? s[t - off] : 0;
        __syncthreads();
        s[t] += u;
        __syncthreads();
    }
    if (t < NB) {
        const int excl = s[t] - v;
        bptr[t] = excl;
        bcursor[t] = excl;
    }
    if (t == NB - 1) bptr[NB] = E;
}

// ---- pass B1: block-local counting sort of a 4096-edge chunk into bucket
//      segments of bed[] (one global cursor atomic per (block,bucket)) ----
__global__ void __launch_bounds__(256) k_bscatter(
        const int* __restrict__ src, const int* __restrict__ dst,
        const float* __restrict__ ew, const int* __restrict__ bptr,
        int* __restrict__ bcursor, int2* __restrict__ bed, int E, int NB) {
    __shared__ int hist[NBMAX], scn[NBMAX], cur[NBMAX], base[NBMAX];
    __shared__ int2 sorted[CHUNK];
    __shared__ unsigned short bof[CHUNK];
    const int t = threadIdx.x;
    const int c0 = blockIdx.x * CHUNK;
    const int n = (E - c0 < CHUNK) ? (E - c0) : CHUNK;

    for (int l = t; l < NBMAX; l += 256) hist[l] = 0;
    __syncthreads();
    for (int i = t; i < n; i += 256)
        atomicAdd(&hist[((unsigned)dst[c0 + i]) >> 8], 1);
    __syncthreads();
    // inclusive scan (512 bins, 256 threads, 2 elems each)
    scn[t] = hist[t];
    scn[t + 256] = hist[t + 256];
    __syncthreads();
#pragma unroll
    for (int off = 1; off < 512; off <<= 1) {
        const int i1 = t + 256;
        const int v0 = (t >= off) ? scn[t - off] : 0;
        const int v1 = scn[i1 - off];   // i1-off >= 0 always (off<=256)
        __syncthreads();
        scn[t] += v0;
        scn[i1] += v1;
        __syncthreads();
    }
    cur[t] = scn[t] - hist[t];
    cur[t + 256] = scn[t + 256] - hist[t + 256];
    __syncthreads();
    // local sort into LDS
    for (int i = t; i < n; i += 256) {
        const int s  = src[c0 + i];
        const int d  = dst[c0 + i];
        const float w = ew[c0 + i];
        const int bk = ((unsigned)d) >> 8;
        const int slot = atomicAdd(&cur[bk], 1);
        sorted[slot] = make_int2(s | ((d & 255) << 18), __float_as_int(w));
        bof[slot] = (unsigned short)bk;
    }
    __syncthreads();
    // reserve global space per bucket
    for (int l = t; l < NB; l += 256)
        base[l] = hist[l] ? atomicAdd(&bcursor[l], hist[l]) : 0;
    __syncthreads();
    // segmented-contiguous write-out
    for (int i = t; i < n; i += 256) {
        const int bk = bof[i];
        const int excl = scn[bk] - hist[bk];
        bed[base[bk] + (i - excl)] = sorted[i];
    }
}

// ---- pass C: per-bucket sort -> final ed[], rowptr, dis (all LDS-local) ----
__global__ void __launch_bounds__(256) k_bsort(
        const int2* __restrict__ bed, const int* __restrict__ bptr,
        int* __restrict__ rowptr, float* __restrict__ dis,
        int2* __restrict__ ed, int N, int E, int NB) {
    __shared__ int hist[256], scn[256], cur[256];
    __shared__ float degw[256];
    const int t = threadIdx.x;
    const int b = blockIdx.x;
    const int r0 = b << 8;
    const int L = (N - r0 < 256) ? (N - r0) : 256;
    const int e0 = bptr[b];
    const int M = bptr[b + 1] - e0;

    hist[t] = 0;
    degw[t] = 0.0f;
    __syncthreads();
    for (int i = t; i < M; i += 256) {
        const int2 rec = bed[e0 + i];
        const int dl = ((unsigned)rec.x) >> 18;
        atomicAdd(&hist[dl], 1);
        atomicAdd(&degw[dl], __int_as_float(rec.y));
    }
    __syncthreads();
    scn[t] = hist[t];
    __syncthreads();
#pragma unroll
    for (int off = 1; off < 256; off <<= 1) {
        int u = (t >= off) ? scn[t - off] : 0;
        __syncthreads();
        scn[t] += u;
        __syncthreads();
    }
    const int excl = scn[t] - hist[t];
    if (t < L) {
        rowptr[r0 + t] = e0 + excl;
        dis[r0 + t] = rsqrtf(1.0f + degw[t]);   // self-loop weight 1 => deg >= 1
    }
    cur[t] = excl;
    __syncthreads();
    for (int i = t; i < M; i += 256) {
        const int2 rec = bed[e0 + i];
        const int dl = ((unsigned)rec.x) >> 18;
        const int slot = atomicAdd(&cur[dl], 1);
        ed[e0 + slot] = make_int2(rec.x & 0x3FFFF, rec.y);
    }
    if (b == 0 && t == 0) rowptr[N] = E;
}

// ======================================================================
// Compute kernels (factorized norm: h rows pre-scaled by dis[row])
// ======================================================================

// h1s = (x @ W1) * dis[row]
__global__ void __launch_bounds__(256) k_gemm1(
        const float* __restrict__ x, const float* __restrict__ W1,
        const float* __restrict__ dis, float* __restrict__ h1s, int N) {
    __shared__ float xs[64 * XS_PAD];
    __shared__ float W1s[F_IN * H_MID];
    const int t = threadIdx.x;
    for (int i = t; i < F_IN * H_MID; i += 256) W1s[i] = W1[i];
    const int c  = t & 15;
    const int r0 = t >> 4;
    for (long long tile = (long long)blockIdx.x * 64; tile < N;
         tile += (long long)gridDim.x * 64) {
        const int rows = (int)((N - tile < 64) ? (N - tile) : 64);
        __syncthreads();
        const int nf4 = rows * (F_IN / 4);
        const float4* xg = reinterpret_cast<const float4*>(x + tile * F_IN);
        for (int i = t; i < nf4; i += 256) {
            const int r  = i >> 5;
            const int k4 = i & 31;
            *reinterpret_cast<float4*>(&xs[r * XS_PAD + k4 * 4]) = xg[i];
        }
        __syncthreads();
        for (int rr = r0; rr < rows; rr += 16) {
            const float* xr = &xs[rr * XS_PAD];
            float acc = 0.0f;
#pragma unroll
            for (int k4 = 0; k4 < F_IN / 4; ++k4) {
                float4 v = *reinterpret_cast<const float4*>(&xr[k4 * 4]);
                acc = fmaf(v.x, W1s[(k4 * 4 + 0) * H_MID + c], acc);
                acc = fmaf(v.y, W1s[(k4 * 4 + 1) * H_MID + c], acc);
                acc = fmaf(v.z, W1s[(k4 * 4 + 2) * H_MID + c], acc);
                acc = fmaf(v.w, W1s[(k4 * 4 + 3) * H_MID + c], acc);
            }
            const long long row = tile + rr;
            h1s[row * H_MID + c] = acc * dis[row];
        }
    }
}

// a1 = relu(b1 + dis[node]*(h1s[node] + sum_edges h1s[src]*ew))   (RELU fused)
template <int LOG, bool RELU>
__global__ void k_agg_csr(const int* __restrict__ rowptr, const int2* __restrict__ ed,
                          const float* __restrict__ h, const float* __restrict__ dis,
                          const float* __restrict__ bias, float* __restrict__ out, int N) {
    const int CH = 1 << LOG;
    const long long t = (long long)blockIdx.x * blockDim.x + threadIdx.x;
    const int node = (int)(t >> LOG);
    const int c = (int)(t & (CH - 1));
    if (node >= N) return;
    const int beg = rowptr[node];
    const int end = rowptr[node + 1];
    float acc0 = h[(long long)node * CH + c];   // self loop (weight 1)
    float acc1 = 0.0f;
    int e = beg;
    for (; e + 1 < end; e += 2) {
        int2 p0 = ed[e];
        int2 p1 = ed[e + 1];
        acc0 = fmaf(h[(long long)p0.x * CH + c], __int_as_float(p0.y), acc0);
        acc1 = fmaf(h[(long long)p1.x * CH + c], __int_as_float(p1.y), acc1);
    }
    if (e < end) {
        int2 p = ed[e];
        acc0 = fmaf(h[(long long)p.x * CH + c], __int_as_float(p.y), acc0);
    }
    float r = fmaf(acc0 + acc1, dis[node], bias[c]);
    if (RELU) r = fmaxf(r, 0.0f);
    out[(long long)node * CH + c] = r;
}

// h2s = (a1 @ W2) * dis[row]   (a1 already relu'd)
__global__ void k_gemm2(const float* __restrict__ a1, const float* __restrict__ W2,
                        const float* __restrict__ dis, float* __restrict__ h2s, int N) {
    __shared__ float W2s[H_MID * C_OUT];
    if (threadIdx.x < H_MID * C_OUT) W2s[threadIdx.x] = W2[threadIdx.x];
    __syncthreads();
    const int c   = threadIdx.x & 7;
    const int lr  = threadIdx.x >> 3;
    const int rpb = blockDim.x >> 3;
    for (long long row = (long long)blockIdx.x * rpb + lr; row < N;
         row += (long long)gridDim.x * rpb) {
        const float4* ar = reinterpret_cast<const float4*>(a1 + row * H_MID);
        float acc = 0.0f;
#pragma unroll
        for (int k4 = 0; k4 < H_MID / 4; ++k4) {
            float4 v = ar[k4];
            acc = fmaf(v.x, W2s[(k4 * 4 + 0) * C_OUT + c], acc);
            acc = fmaf(v.y, W2s[(k4 * 4 + 1) * C_OUT + c], acc);
            acc = fmaf(v.z, W2s[(k4 * 4 + 2) * C_OUT + c], acc);
            acc = fmaf(v.w, W2s[(k4 * 4 + 3) * C_OUT + c], acc);
        }
        h2s[row * C_OUT + c] = acc * dis[row];
    }
}

// ======================================================================
// Fallback: round-2 atomic pipeline (verbatim), used only on size guards
// ======================================================================
__global__ void k_init_deg(float* __restrict__ deg, int N) {
    int i = blockIdx.x * blockDim.x + threadIdx.x;
    if (i < N) deg[i] = 1.0f;
}
__global__ void k_scatter_deg(const int* __restrict__ dst, const float* __restrict__ ew,
                              float* __restrict__ deg, int E) {
    int e = blockIdx.x * blockDim.x + threadIdx.x;
    if (e < E) atomicAdd(&deg[dst[e]], ew[e]);
}
__global__ void k_rsqrt(float* __restrict__ deg, int N) {
    int i = blockIdx.x * blockDim.x + threadIdx.x;
    if (i < N) {
        float v = deg[i];
        deg[i] = (v > 0.0f) ? rsqrtf(v) : 0.0f;
    }
}
__global__ void __launch_bounds__(256) k_gemm1_r2(
        const float* __restrict__ x, const float* __restrict__ W1,
        const float* __restrict__ b1, const float* __restrict__ dis,
        float* __restrict__ h1, float* __restrict__ a1, int N) {
    __shared__ float xs[64 * XS_PAD];
    __shared__ float W1s[F_IN * H_MID];
    const int t = threadIdx.x;
    for (int i = t; i < F_IN * H_MID; i += 256) W1s[i] = W1[i];
    const int c  = t & 15;
    const int r0 = t >> 4;
    for (long long tile = (long long)blockIdx.x * 64; tile < N;
         tile += (long long)gridDim.x * 64) {
        const int rows = (int)((N - tile < 64) ? (N - tile) : 64);
        __syncthreads();
        const int nf4 = rows * (F_IN / 4);
        const float4* xg = reinterpret_cast<const float4*>(x + tile * F_IN);
        for (int i = t; i < nf4; i += 256) {
            const int r  = i >> 5;
            const int k4 = i & 31;
            *reinterpret_cast<float4*>(&xs[r * XS_PAD + k4 * 4]) = xg[i];
        }
        __syncthreads();
        for (int rr = r0; rr < rows; rr += 16) {
            const float* xr = &xs[rr * XS_PAD];
            float acc = 0.0f;
#pragma unroll
            for (int k4 = 0; k4 < F_IN / 4; ++k4) {
                float4 v = *reinterpret_cast<const float4*>(&xr[k4 * 4]);
                acc = fmaf(v.x, W1s[(k4 * 4 + 0) * H_MID + c], acc);
                acc = fmaf(v.y, W1s[(k4 * 4 + 1) * H_MID + c], acc);
                acc = fmaf(v.z, W1s[(k4 * 4 + 2) * H_MID + c], acc);
                acc = fmaf(v.w, W1s[(k4 * 4 + 3) * H_MID + c], acc);
            }
            const long long row = tile + rr;
            h1[row * H_MID + c] = acc;
            float di = dis[row];
            a1[row * H_MID + c] = fmaf(acc, di * di, b1[c]);
        }
    }
}
template <int CH>
__global__ void k_agg_at(const int* __restrict__ src, const int* __restrict__ dst,
                         const float* __restrict__ ew, const float* __restrict__ dis,
                         const float* __restrict__ h, float* __restrict__ out, long long E) {
    const int LOG = (CH == 16) ? 4 : 3;
    const long long total  = E << LOG;
    const long long stride = (long long)gridDim.x * blockDim.x;
    for (long long idx = (long long)blockIdx.x * blockDim.x + threadIdx.x; idx < total;
         idx += stride) {
        const long long e = idx >> LOG;
        const int c = (int)(idx & (CH - 1));
        const int s = src[e];
        const int d = dst[e];
        const float norm = dis[s] * ew[e] * dis[d];
        atomicAdd(out + (long long)d * CH + c, h[(long long)s * CH + c] * norm);
    }
}
__global__ void k_gemm2_r2(const float* __restrict__ a1, const float* __restrict__ W2,
                           const float* __restrict__ b2, const float* __restrict__ dis,
                           float* __restrict__ h2, float* __restrict__ out, int N) {
    __shared__ float W2s[H_MID * C_OUT];
    if (threadIdx.x < H_MID * C_OUT) W2s[threadIdx.x] = W2[threadIdx.x];
    __syncthreads();
    const int c   = threadIdx.x & 7;
    const int lr  = threadIdx.x >> 3;
    const int rpb = blockDim.x >> 3;
    for (long long row = (long long)blockIdx.x * rpb + lr; row < N;
         row += (long long)gridDim.x * rpb) {
        const float4* ar = reinterpret_cast<const float4*>(a1 + row * H_MID);
        float acc = 0.0f;
#pragma unroll
        for (int k4 = 0; k4 < H_MID / 4; ++k4) {
            float4 v = ar[k4];
            acc = fmaf(fmaxf(v.x, 0.0f), W2s[(k4 * 4 + 0) * C_OUT + c], acc);
            acc = fmaf(fmaxf(v.y, 0.0f), W2s[(k4 * 4 + 1) * C_OUT + c], acc);
            acc = fmaf(fmaxf(v.z, 0.0f), W2s[(k4 * 4 + 2) * C_OUT + c], acc);
            acc = fmaf(fmaxf(v.w, 0.0f), W2s[(k4 * 4 + 3) * C_OUT + c], acc);
        }
        h2[row * C_OUT + c] = acc;
        float di = dis[row];
        out[row * C_OUT + c] = fmaf(acc, di * di, b2[c]);
    }
}

extern "C" void kernel_launch(void* const* d_in, const int* in_sizes, int n_in,
                              void* d_out, int out_size, void* d_ws, size_t ws_size,
                              hipStream_t stream) {
    const float* x  = (const float*)d_in[0];
    const int*   ei = (const int*)d_in[1];
    const float* ew = (const float*)d_in[2];
    const float* W1 = (const float*)d_in[3];
    const float* b1 = (const float*)d_in[4];
    const float* W2 = (const float*)d_in[5];
    const float* b2 = (const float*)d_in[6];
    float* out = (float*)d_out;

    const int H   = in_sizes[4];            // 16
    const int Fin = in_sizes[3] / H;        // 128
    const int N   = in_sizes[0] / Fin;      // 100000
    const int E   = in_sizes[2];            // 1600000
    const int* src = ei;
    const int* dst = ei + E;
    (void)n_in; (void)out_size;

    char* ws = (char*)d_ws;
    size_t off = 0;
    auto alloc = [&](size_t bytes) {
        void* p = ws + off;
        off = (off + bytes + 255) & ~(size_t)255;
        return p;
    };
    float* dis    = (float*)alloc((size_t)N * sizeof(float));
    float* h1s    = (float*)alloc((size_t)N * H_MID * sizeof(float));
    int*   rowptr = (int*)alloc(((size_t)N + 1) * sizeof(int));
    int*   bcount = (int*)alloc(NBMAX * sizeof(int));
    int*   bptr   = (int*)alloc((NBMAX + 1) * sizeof(int));
    int*   bcursor= (int*)alloc(NBMAX * sizeof(int));
    int2*  bed    = (int2*)alloc((size_t)E * sizeof(int2));
    int2*  ed     = (int2*)alloc((size_t)E * sizeof(int2));
    // a1 / h2s alias bed (dead after k_bsort, reborn as layer activations)
    float* a1  = (float*)bed;
    float* h2s = (float*)bed + (size_t)N * H_MID;
    const size_t needed = off;

    const int B = 256;
    const int NB = (N + 255) >> 8;
    const bool fast_ok = (needed <= ws_size) && (N <= 131072) && (NB <= NBMAX);

    if (fast_ok) {
        // ---- CSR build (atomic-light bucket sort) ----
        hipMemsetAsync(bcount, 0, NBMAX * sizeof(int), stream);
        k_bhist<<<512, B, 0, stream>>>(dst, bcount, E, NB);
        k_bscan<<<1, 512, 0, stream>>>(bcount, bptr, bcursor, NB, E);
        k_bscatter<<<(E + CHUNK - 1) / CHUNK, B, 0, stream>>>(
            src, dst, ew, bptr, bcursor, bed, E, NB);
        k_bsort<<<NB, B, 0, stream>>>(bed, bptr, rowptr, dis, ed, N, E, NB);
        // ---- layer 1 ----
        k_gemm1<<<(N + 63) / 64, B, 0, stream>>>(x, W1, dis, h1s, N);
        k_agg_csr<4, true><<<(int)(((long long)N * H_MID + B - 1) / B), B, 0, stream>>>(
            rowptr, ed, h1s, dis, b1, a1, N);
        // ---- layer 2 ----
        k_gemm2<<<(N + 31) / 32, B, 0, stream>>>(a1, W2, dis, h2s, N);
        k_agg_csr<3, false><<<(int)(((long long)N * C_OUT + B - 1) / B), B, 0, stream>>>(
            rowptr, ed, h2s, dis, b2, out, N);
    } else {
        // ---- fallback: round-2 atomic path (needs ~17 MB) ----
        off = 0;
        float* disF = (float*)alloc((size_t)N * sizeof(float));
        float* h1   = (float*)alloc((size_t)N * H_MID * sizeof(float));
        float* a1F  = (float*)alloc((size_t)N * H_MID * sizeof(float));
        float* h2   = (float*)alloc((size_t)N * C_OUT * sizeof(float));
        k_init_deg<<<(N + B - 1) / B, B, 0, stream>>>(disF, N);
        k_scatter_deg<<<(E + B - 1) / B, B, 0, stream>>>(dst, ew, disF, E);
        k_rsqrt<<<(N + B - 1) / B, B, 0, stream>>>(disF, N);
        k_gemm1_r2<<<(N + 63) / 64, B, 0, stream>>>(x, W1, b1, disF, h1, a1F, N);
        k_agg_at<H_MID><<<8192, B, 0, stream>>>(src, dst, ew, disF, h1, a1F, E);
        k_gemm2_r2<<<(N + 31) / 32, B, 0, stream>>>(a1F, W2, b2, disF, h2, out, N);
        k_agg_at<C_OUT><<<8192, B, 0, stream>>>(src, dst, ew, disF, h2, out, E);
    }
}